// Round 16
// baseline (290.006 us; speedup 1.0000x reference)
//
#include <hip/hip_runtime.h>
#include <hip/hip_bf16.h>
#include <cstdint>

typedef unsigned short ushortT;
typedef __attribute__((ext_vector_type(8))) short short8;
typedef __attribute__((ext_vector_type(4))) float f32x4;
typedef __attribute__((ext_vector_type(4))) unsigned short us4;

__device__ __forceinline__ ushortT f2bf(float f) {
  union { float f; unsigned u; } v; v.f = f;
  unsigned r = (v.u + 0x7FFFu + ((v.u >> 16) & 1u)) >> 16;
  return (ushortT)r;
}

__device__ __forceinline__ void gl_lds16(const void* g, void* l) {
  __builtin_amdgcn_global_load_lds(
      (__attribute__((address_space(1))) void*)g,
      (__attribute__((address_space(3))) void*)l, 16, 0, 0);
}

// ==== gemm_mg: blocks [0,2048) = r8/r13 gemm256 (proven path, unchanged);
// blocks [2048,2176) = mgemm128sk as 2x256-thread groups/block, now with the
// granule swizzle (stage: src col ^= (l>>3)&3; read: fr-dependent) that
// zeroed conflicts in gemm256.
__global__ __launch_bounds__(512, 2) void gemm_mg(
    const ushortT* __restrict__ A, const ushortT* __restrict__ B,
    float* __restrict__ outF, const float* __restrict__ bias,
    const ushortT* __restrict__ T, float* __restrict__ pbuf)
{
  __shared__ ushortT smem[36864];  // 73728 B pool
  const int tid = threadIdx.x;
  const int bid = blockIdx.x;
  constexpr int N = 2048, K = 1024;

  if (bid < 2048) {
    ushortT(*sA)[256 * 32] = (ushortT(*)[256 * 32])smem;
    ushortT(*sB)[128 * 32] = (ushortT(*)[128 * 32])(smem + 3 * 256 * 32);

    const int wv = tid >> 6, l = tid & 63;
    const int wm = wv >> 1, wn = wv & 1;

    const int xcd = bid & 7, i = bid >> 3;
    const int n0 = (i & 15) * 128;
    const int m0 = (xcd * 16 + (i >> 4)) * 256;
    const int NK = K >> 5;

    f32x4 acc[4][4] = {};

    const ushortT* Ab = A + (size_t)m0 * (size_t)K;
    const ushortT* Bb = B + (size_t)n0 * (size_t)K;

    const int sr = tid >> 2;
    const int sg = tid & 3;
    const int gsw = sg ^ ((sr >> 1) & 3);

    auto stage = [&](int kt) {
      const int b = kt % 3;
      const size_t kof = (size_t)((kt << 5) + (gsw << 3));
      gl_lds16(Ab + (size_t)sr * (size_t)K + kof,         &sA[b][(wv * 16) * 32]);
      gl_lds16(Ab + (size_t)(128 + sr) * (size_t)K + kof, &sA[b][(128 + wv * 16) * 32]);
      gl_lds16(Bb + (size_t)sr * (size_t)K + kof,         &sB[b][(wv * 16) * 32]);
    };

    const int fr = l & 15;
    const int colsw = (((l >> 4) ^ ((fr >> 1) & 3)) << 3);

    stage(0);
    stage(1);

    for (int kt = 0; kt < NK; ++kt) {
      if (kt + 1 < NK) asm volatile("s_waitcnt vmcnt(3)" ::: "memory");
      else             asm volatile("s_waitcnt vmcnt(0)" ::: "memory");
      __builtin_amdgcn_s_barrier();
      if (kt + 2 < NK) stage(kt + 2);

      const int bc = kt % 3;
      short8 av[4], bv8[4];
#pragma unroll
      for (int fi = 0; fi < 4; ++fi)
        av[fi] = *(const short8*)&sA[bc][(wm * 64 + fi * 16 + fr) * 32 + colsw];
#pragma unroll
      for (int fj = 0; fj < 4; ++fj)
        bv8[fj] = *(const short8*)&sB[bc][(wn * 64 + fj * 16 + fr) * 32 + colsw];

      __builtin_amdgcn_s_setprio(1);
#pragma unroll
      for (int fi = 0; fi < 4; ++fi)
#pragma unroll
        for (int fj = 0; fj < 4; ++fj)
          acc[fi][fj] = __builtin_amdgcn_mfma_f32_16x16x32_bf16(
              av[fi], bv8[fj], acc[fi][fj], 0, 0, 0);
      __builtin_amdgcn_s_setprio(0);
    }

    const int cc = l & 15, r4 = (l >> 4) * 4;
    float bvv[4];
#pragma unroll
    for (int fj = 0; fj < 4; ++fj) bvv[fj] = bias[n0 + wn * 64 + fj * 16 + cc];

    float* lbuf = (float*)smem;
#pragma unroll
    for (int s = 0; s < 2; ++s) {
      __syncthreads();
      if ((wm >> 1) == s) {
#pragma unroll
        for (int fi = 0; fi < 4; ++fi)
#pragma unroll
          for (int r = 0; r < 4; ++r) {
            const int row = (wm & 1) * 64 + fi * 16 + r4 + r;
#pragma unroll
            for (int fj = 0; fj < 4; ++fj)
              lbuf[row * 132 + wn * 64 + fj * 16 + cc] = acc[fi][fj][r] + bvv[fj];
          }
      }
      __syncthreads();
#pragma unroll
      for (int k = 0; k < 8; ++k) {
        const int f = k * 512 + tid;
        const int row = f >> 5, c4 = f & 31;
        f32x4 v = *(const f32x4*)&lbuf[row * 132 + c4 * 4];
        __builtin_nontemporal_store(
            v, (f32x4*)&outF[(size_t)(m0 + s * 128 + row) * (size_t)N + n0 + c4 * 4]);
      }
    }
  } else {
    // ---- mgemm: M-partials = sdT sdT^T, two 256-thread groups per block ----
    const int tt = bid - 2048;            // 0..127
    const int g = tid >> 8;               // group 0/1
    const int lt = tid & 255;
    const int q = tt * 2 + g;             // 0..255 tile index
    const int i0 = (q & 7) * 128;
    const int j0 = ((q >> 3) & 7) * 128;
    const int kt0 = (q >> 6) * 64;
    constexpr int Kt = 8192, Dm = 1024;

    ushortT* pool = smem + g * 16384;     // 32768 B per group
    ushortT(*sA)[128 * 32] = (ushortT(*)[128 * 32])pool;
    ushortT(*sB)[128 * 32] = (ushortT(*)[128 * 32])(pool + 2 * 128 * 32);

    const int w = lt >> 6, l = lt & 63;
    const int wr = w >> 1, wc = w & 1;
    f32x4 acc[4][4] = {};

    const int sgm = ((l & 3) ^ ((l >> 3) & 3)) << 3;  // swizzled src granule

    auto stage = [&](int buf, int kt) {
      const size_t col = (size_t)((kt << 5) + sgm);
      const int rb = w * 16 + (l >> 2);
#pragma unroll
      for (int c = 0; c < 2; ++c) {
        gl_lds16(T + (size_t)(i0 + c * 64 + rb) * (size_t)Kt + col,
                 &sA[buf][c * 2048 + w * 512]);
        gl_lds16(T + (size_t)(j0 + c * 64 + rb) * (size_t)Kt + col,
                 &sB[buf][c * 2048 + w * 512]);
      }
    };

    const int fr = l & 15;
    const int colsw = (((l >> 4) ^ ((fr >> 1) & 3)) << 3);

    stage(0, kt0);
    __syncthreads();

    for (int t = 0; t < 64; ++t) {
      const int buf = t & 1;
      if (t + 1 < 64) stage(buf ^ 1, kt0 + t + 1);
      short8 a[4], b[4];
#pragma unroll
      for (int f = 0; f < 4; ++f) {
        a[f] = *(const short8*)&sA[buf][(wr * 64 + f * 16 + fr) * 32 + colsw];
        b[f] = *(const short8*)&sB[buf][(wc * 64 + f * 16 + fr) * 32 + colsw];
      }
#pragma unroll
      for (int fi = 0; fi < 4; ++fi)
#pragma unroll
        for (int fj = 0; fj < 4; ++fj)
          acc[fi][fj] = __builtin_amdgcn_mfma_f32_16x16x32_bf16(
              a[fi], b[fj], acc[fi][fj], 0, 0, 0);
      __syncthreads();
    }

    const int r4 = (l >> 4) * 4, cc = l & 15;
    float* out = pbuf + ((size_t)(q >> 6) << 20);
#pragma unroll
    for (int fi = 0; fi < 4; ++fi)
#pragma unroll
      for (int r = 0; r < 4; ++r) {
        const int gi = i0 + wr * 64 + fi * 16 + r4 + r;
#pragma unroll
        for (int fj = 0; fj < 4; ++fj) {
          const int gj = j0 + wc * 64 + fj * 16 + cc;
          out[(size_t)gi * (size_t)Dm + gj] = acc[fi][fj][r];
        }
      }
  }
}

// ===== fused_sd + cvt_x: blocks [0,128) W@Q | [128,640) sd | [640,2688) =====
// cvt_x stream overlaps the GEMM blocks. GEMM path now granule-swizzled
// (same derivation as gemm256 -> 0 conflicts). tbuf aliased over sA/sB.
__global__ __launch_bounds__(256) void fused_sd(
    const ushortT* __restrict__ wbf, const ushortT* __restrict__ qT,
    ushortT* __restrict__ fusedbf,
    const ushortT* __restrict__ selbf, const ushortT* __restrict__ pbf,
    const float* __restrict__ addend,
    float* __restrict__ S2, float* __restrict__ S4,
    ushortT* __restrict__ sdT,
    const float* __restrict__ x, ushortT* __restrict__ xbf)
{
  __shared__ ushortT smem[17408];  // 34816 B: sA|sB (32768) aliased by tbuf
  const int tid = threadIdx.x;
  const int bid = blockIdx.x;

  if (bid >= 640) {  // ---- cvt_x: 2048 blocks, 201 MB stream ----
    const f32x4* in4 = (const f32x4*)x;
    for (size_t i = (size_t)(bid - 640) * 256 + tid; i < 8388608ULL;
         i += 2048ULL * 256) {
      f32x4 v = __builtin_nontemporal_load(&in4[i]);
      us4 o = { f2bf(v[0]), f2bf(v[1]), f2bf(v[2]), f2bf(v[3]) };
      *(us4*)(xbf + i * 4) = o;
    }
    return;
  }

  ushortT(*sA)[128 * 32] = (ushortT(*)[128 * 32])smem;
  ushortT(*sB)[128 * 32] = (ushortT(*)[128 * 32])(smem + 2 * 128 * 32);
  ushortT* tbuf = smem;  // epilogue-only alias

  const int w = tid >> 6, l = tid & 63;
  const int wr = w >> 1, wc = w & 1;
  constexpr int K = 1024, NK = 32, N = 1024;

  const bool isF = bid < 128;
  const int q = isF ? bid : bid - 128;
  const int m0 = isF ? (q & 15) * 128 : (q & 63) * 128;
  const int n0 = isF ? (q >> 4) * 128 : (q >> 6) * 128;
  const ushortT* A = isF ? wbf : selbf;
  const ushortT* B = isF ? qT : pbf;

  f32x4 acc[4][4] = {};

  const int sgm = ((l & 3) ^ ((l >> 3) & 3)) << 3;  // swizzled src granule

  auto stage = [&](int buf, int kt) {
    const size_t colA = (size_t)((kt << 5) + sgm);
    const int rb = w * 16 + (l >> 2);
#pragma unroll
    for (int c = 0; c < 2; ++c) {
      gl_lds16(A + (size_t)(m0 + c * 64 + rb) * (size_t)K + colA,
               &sA[buf][c * 2048 + w * 512]);
      gl_lds16(B + (size_t)(n0 + c * 64 + rb) * (size_t)K + colA,
               &sB[buf][c * 2048 + w * 512]);
    }
  };

  const int fr = l & 15;
  const int colsw = (((l >> 4) ^ ((fr >> 1) & 3)) << 3);

  stage(0, 0);
  __syncthreads();

  for (int kt = 0; kt < NK; ++kt) {
    const int buf = kt & 1;
    if (kt + 1 < NK) stage(buf ^ 1, kt + 1);
    short8 a[4], b[4];
#pragma unroll
    for (int f = 0; f < 4; ++f) {
      a[f] = *(const short8*)&sA[buf][(wr * 64 + f * 16 + fr) * 32 + colsw];
      b[f] = *(const short8*)&sB[buf][(wc * 64 + f * 16 + fr) * 32 + colsw];
    }
#pragma unroll
    for (int fi = 0; fi < 4; ++fi)
#pragma unroll
      for (int fj = 0; fj < 4; ++fj)
        acc[fi][fj] = __builtin_amdgcn_mfma_f32_16x16x32_bf16(
            a[fi], b[fj], acc[fi][fj], 0, 0, 0);
    __syncthreads();
  }

  const int r4 = (l >> 4) * 4, cc = l & 15;

  if (isF) {
#pragma unroll
    for (int fi = 0; fi < 4; ++fi)
#pragma unroll
      for (int r = 0; r < 4; ++r) {
        const size_t gm = (size_t)(m0 + wr * 64 + fi * 16 + r4 + r);
#pragma unroll
        for (int fj = 0; fj < 4; ++fj) {
          const int gn = n0 + wc * 64 + fj * 16 + cc;
          fusedbf[gm * (size_t)N + gn] = f2bf(acc[fi][fj][r]);
        }
      }
  } else {
#pragma unroll
    for (int fi = 0; fi < 4; ++fi)
#pragma unroll
      for (int r = 0; r < 4; ++r) {
        const int row = wr * 64 + fi * 16 + r4 + r;
        const size_t gm = (size_t)(m0 + row);
        float rs2 = 0.f, rs4 = 0.f;
#pragma unroll
        for (int fj = 0; fj < 4; ++fj) {
          const int col = wc * 64 + fj * 16 + cc;
          float sd = acc[fi][fj][r] + addend[gm * (size_t)N + n0 + col];
          tbuf[col * 136 + row] = f2bf(sd);
          float s2 = sd * sd;
          rs2 += s2;
          rs4 += s2 * s2;
        }
#pragma unroll
        for (int mk = 1; mk < 16; mk <<= 1) {
          rs2 += __shfl_xor(rs2, mk, 16);
          rs4 += __shfl_xor(rs4, mk, 16);
        }
        if (cc == 0) { atomicAdd(&S2[gm], rs2); atomicAdd(&S4[gm], rs4); }
      }
    __syncthreads();
#pragma unroll
    for (int i = 0; i < 8; ++i) {
      const int er = i * 16 + (tid >> 4);
      const int nc = (tid & 15) * 8;
      short8 v = *(const short8*)&tbuf[er * 136 + nc];
      *(short8*)&sdT[(size_t)(n0 + er) * 8192 + m0 + nc] = v;
    }
  }
}

// ---- merged finalize: grad reduce (blocks 0..1023) + losses (block 1024) ----
__global__ __launch_bounds__(256) void finalize(
    const float* __restrict__ pbuf, float* __restrict__ grad, float invN,
    const float* __restrict__ S2, const float* __restrict__ S4,
    float* __restrict__ losses)
{
  __shared__ double red0[256];
  __shared__ double red1[256];
  const int t = threadIdx.x;
  if (blockIdx.x < 1024) {
    const int i = blockIdx.x * 256 + t;
    const size_t base = (size_t)i * 4;
    f32x4 s = *(const f32x4*)(pbuf + base) + *(const f32x4*)(pbuf + base + (1u << 20)) +
              *(const f32x4*)(pbuf + base + (2u << 20)) + *(const f32x4*)(pbuf + base + (3u << 20));
    const int row = (int)(base >> 10), c0 = (int)(base & 1023);
    f32x4 o;
#pragma unroll
    for (int j = 0; j < 4; ++j)
      o[j] = 0.5f * (s[j] * invN) - ((row == c0 + j) ? 0.5f : 0.0f);
    *(f32x4*)(grad + base) = o;
  } else {
    double ca = 0.0, wa = 0.0;
    for (int i = t; i < 8192; i += 256) {
      double s2 = (double)S2[i], s4 = (double)S4[i];
      ca += s2 * s2 - s4;
      wa += s4 - 2.0 * s2 + 1024.0;
    }
    red0[t] = ca; red1[t] = wa;
    __syncthreads();
    for (int s = 128; s > 0; s >>= 1) {
      if (t < s) { red0[t] += red0[t + s]; red1[t] += red1[t + s]; }
      __syncthreads();
    }
    if (t == 0) {
      const double inv = 1.0 / (8192.0 * 1024.0 * 1024.0);
      losses[0] = (float)(red0[0] * inv);
      losses[1] = (float)(red1[0] * inv);
    }
  }
}

// ==== prep (no cvt_x): cvt_w | make P | transpose Q | zero | gather =========
__global__ __launch_bounds__(256) void prep_all(
    const float* __restrict__ x, const float* __restrict__ weight,
    const float* __restrict__ decorr, const int* __restrict__ idx,
    ushortT* __restrict__ wbf, ushortT* __restrict__ qT,
    ushortT* __restrict__ pbf, float* __restrict__ S2S4,
    float* __restrict__ self32, ushortT* __restrict__ selbf)
{
  __shared__ float t[64][65];
  const int bid = blockIdx.x;
  const int tix = threadIdx.x;
  if (bid < 512) {
    const f32x4* in4 = (const f32x4*)weight;
    for (size_t i = (size_t)bid * 256 + tix; i < 524288ULL; i += 512ULL * 256) {
      f32x4 v = in4[i];
      us4 o = { f2bf(v[0]), f2bf(v[1]), f2bf(v[2]), f2bf(v[3]) };
      *(us4*)(wbf + i * 4) = o;
    }
  } else if (bid < 1024) {
    const size_t base = ((size_t)(bid - 512) * 256 + tix) * 8;
    const int e = (int)(base >> 10);
    const int d0 = (int)(base & 1023);
    short8 v;
#pragma unroll
    for (int j = 0; j < 8; ++j) {
      float f = decorr[base + j] - ((e == d0 + j) ? 1.0f : 0.0f);
      v[j] = (short)f2bf(f);
    }
    *(short8*)(pbf + base) = v;
  } else if (bid < 1280) {
    const int tq = bid - 1024;
    const int bi = tq & 15, bj = tq >> 4;
    const int tr = tix >> 4, tc = tix & 15;
#pragma unroll
    for (int i = 0; i < 4; ++i) {
      const int row = i * 16 + tr;
      f32x4 v = *(const f32x4*)&decorr[(size_t)(bi * 64 + row) * 1024 + bj * 64 + tc * 4];
#pragma unroll
      for (int j = 0; j < 4; ++j) t[row][tc * 4 + j] = v[j];
    }
    __syncthreads();
#pragma unroll
    for (int i = 0; i < 4; ++i) {
      const int dr = i * 16 + tr;
      us4 o = { f2bf(t[tc * 4 + 0][dr]), f2bf(t[tc * 4 + 1][dr]),
                f2bf(t[tc * 4 + 2][dr]), f2bf(t[tc * 4 + 3][dr]) };
      *(us4*)&qT[(size_t)(bj * 64 + dr) * 1024 + bi * 64 + tc * 4] = o;
    }
  } else if (bid < 1344) {
    S2S4[(bid - 1280) * 256 + tix] = 0.f;
  } else {
    const int g = bid - 1344;                // 0..8191
    const int b = g >> 10;
    const int row = idx[g] & 4095;
    const f32x4* src = (const f32x4*)(x + ((size_t)b * 4096 + (size_t)row) * 1024);
    f32x4 v = src[tix];
    *(f32x4*)(self32 + (size_t)g * 1024 + tix * 4) = v;
    us4 o = { f2bf(v[0]), f2bf(v[1]), f2bf(v[2]), f2bf(v[3]) };
    *(us4*)(selbf + (size_t)g * 1024 + tix * 4) = o;
  }
}

// ---------------- launch -----------------------------------------------------
extern "C" void kernel_launch(void* const* d_in, const int* in_sizes, int n_in,
                              void* d_out, int out_size, void* d_ws, size_t ws_size,
                              hipStream_t stream) {
  (void)in_sizes; (void)n_in; (void)out_size;
  const float* x = (const float*)d_in[0];
  const float* weight = (const float*)d_in[1];
  const float* bias = (const float*)d_in[2];
  const float* decorr = (const float*)d_in[3];
  const int* sidx = (const int*)d_in[4];

  if (ws_size < 146866176ULL) return;

  char* ws = (char*)d_ws;
  ushortT* xbf     = (ushortT*)(ws);
  ushortT* fusedbf = (ushortT*)(ws + 67108864);
  ushortT* wbf     = (ushortT*)(ws + 71303168);
  ushortT* qT      = (ushortT*)(ws + 75497472);
  ushortT* pbf     = (ushortT*)(ws + 77594624);
  float*   self32  = (float*)  (ws + 79691776);
  ushortT* selbf   = (ushortT*)(ws + 113246208);
  ushortT* sdT     = (ushortT*)(ws + 130023424);
  float*   S2      = (float*)  (ws + 146800640);
  float*   S4      = (float*)  (ws + 146833408);

  float* y = (float*)d_out;
  float* grad = y + 67108864ULL;
  float* losses = grad + 1048576ULL;

  // prep (no cvt_x): cvt_w | P | Q^T | zero | gather
  prep_all<<<dim3(9536), dim3(256), 0, stream>>>(
      x, weight, decorr, sidx, wbf, qT, pbf, S2, self32, selbf);

  // W@Q || sd-GEMM (+S2/S4, sdT) || cvt_x stream
  fused_sd<<<dim3(2688), dim3(256), 0, stream>>>(
      wbf, qT, fusedbf, selbf, pbf, self32, S2, S4, sdT, x, xbf);

  // y = x@fused^T + bias (blocks 0..2047)  ||  M-partials (blocks 2048..2175)
  gemm_mg<<<dim3(2176), dim3(512), 0, stream>>>(
      xbf, fusedbf, y, bias, sdT, self32);

  // grad reduce + losses
  finalize<<<dim3(1025), dim3(256), 0, stream>>>(
      self32, grad, 1.0f / 8192.0f, S2, S4, losses);
}

// Round 17
// 271.139 us; speedup vs baseline: 1.0696x; 1.0696x over previous
//
#include <hip/hip_runtime.h>
#include <hip/hip_bf16.h>
#include <cstdint>

typedef unsigned short ushortT;
typedef __attribute__((ext_vector_type(8))) short short8;
typedef __attribute__((ext_vector_type(4))) float f32x4;
typedef __attribute__((ext_vector_type(4))) unsigned short us4;

__device__ __forceinline__ ushortT f2bf(float f) {
  union { float f; unsigned u; } v; v.f = f;
  unsigned r = (v.u + 0x7FFFu + ((v.u >> 16) & 1u)) >> 16;
  return (ushortT)r;
}

__device__ __forceinline__ void gl_lds16(const void* g, void* l) {
  __builtin_amdgcn_global_load_lds(
      (__attribute__((address_space(1))) void*)g,
      (__attribute__((address_space(3))) void*)l, 16, 0, 0);
}

// ==== gemm_mg: blocks [0,128) = mgemm128sk (FIRST, so they pack alongside
// gemm256's first occupancy wave instead of serializing at the tail);
// blocks [128,2176) = r8/r13 gemm256 (proven path, unchanged).
__global__ __launch_bounds__(512, 2) void gemm_mg(
    const ushortT* __restrict__ A, const ushortT* __restrict__ B,
    float* __restrict__ outF, const float* __restrict__ bias,
    const ushortT* __restrict__ T, float* __restrict__ pbuf)
{
  __shared__ ushortT smem[36864];  // 73728 B pool
  const int tid = threadIdx.x;
  const int bid = blockIdx.x;
  constexpr int N = 2048, K = 1024;

  if (bid >= 128) {
    // ---------------- gemm256: y = x @ fused^T + bias ----------------
    ushortT(*sA)[256 * 32] = (ushortT(*)[256 * 32])smem;
    ushortT(*sB)[128 * 32] = (ushortT(*)[128 * 32])(smem + 3 * 256 * 32);

    const int wv = tid >> 6, l = tid & 63;
    const int wm = wv >> 1, wn = wv & 1;

    const int gb = bid - 128;            // 0..2047, 128%8==0 keeps swizzle
    const int xcd = gb & 7, i = gb >> 3;
    const int n0 = (i & 15) * 128;
    const int m0 = (xcd * 16 + (i >> 4)) * 256;
    const int NK = K >> 5;

    f32x4 acc[4][4] = {};

    const ushortT* Ab = A + (size_t)m0 * (size_t)K;
    const ushortT* Bb = B + (size_t)n0 * (size_t)K;

    const int sr = tid >> 2;
    const int sg = tid & 3;
    const int gsw = sg ^ ((sr >> 1) & 3);

    auto stage = [&](int kt) {
      const int b = kt % 3;
      const size_t kof = (size_t)((kt << 5) + (gsw << 3));
      gl_lds16(Ab + (size_t)sr * (size_t)K + kof,         &sA[b][(wv * 16) * 32]);
      gl_lds16(Ab + (size_t)(128 + sr) * (size_t)K + kof, &sA[b][(128 + wv * 16) * 32]);
      gl_lds16(Bb + (size_t)sr * (size_t)K + kof,         &sB[b][(wv * 16) * 32]);
    };

    const int fr = l & 15;
    const int colsw = (((l >> 4) ^ ((fr >> 1) & 3)) << 3);

    stage(0);
    stage(1);

    for (int kt = 0; kt < NK; ++kt) {
      if (kt + 1 < NK) asm volatile("s_waitcnt vmcnt(3)" ::: "memory");
      else             asm volatile("s_waitcnt vmcnt(0)" ::: "memory");
      __builtin_amdgcn_s_barrier();
      if (kt + 2 < NK) stage(kt + 2);

      const int bc = kt % 3;
      short8 av[4], bv8[4];
#pragma unroll
      for (int fi = 0; fi < 4; ++fi)
        av[fi] = *(const short8*)&sA[bc][(wm * 64 + fi * 16 + fr) * 32 + colsw];
#pragma unroll
      for (int fj = 0; fj < 4; ++fj)
        bv8[fj] = *(const short8*)&sB[bc][(wn * 64 + fj * 16 + fr) * 32 + colsw];

      __builtin_amdgcn_s_setprio(1);
#pragma unroll
      for (int fi = 0; fi < 4; ++fi)
#pragma unroll
        for (int fj = 0; fj < 4; ++fj)
          acc[fi][fj] = __builtin_amdgcn_mfma_f32_16x16x32_bf16(
              av[fi], bv8[fj], acc[fi][fj], 0, 0, 0);
      __builtin_amdgcn_s_setprio(0);
    }

    const int cc = l & 15, r4 = (l >> 4) * 4;
    float bvv[4];
#pragma unroll
    for (int fj = 0; fj < 4; ++fj) bvv[fj] = bias[n0 + wn * 64 + fj * 16 + cc];

    float* lbuf = (float*)smem;
#pragma unroll
    for (int s = 0; s < 2; ++s) {
      __syncthreads();
      if ((wm >> 1) == s) {
#pragma unroll
        for (int fi = 0; fi < 4; ++fi)
#pragma unroll
          for (int r = 0; r < 4; ++r) {
            const int row = (wm & 1) * 64 + fi * 16 + r4 + r;
#pragma unroll
            for (int fj = 0; fj < 4; ++fj)
              lbuf[row * 132 + wn * 64 + fj * 16 + cc] = acc[fi][fj][r] + bvv[fj];
          }
      }
      __syncthreads();
#pragma unroll
      for (int k = 0; k < 8; ++k) {
        const int f = k * 512 + tid;
        const int row = f >> 5, c4 = f & 31;
        f32x4 v = *(const f32x4*)&lbuf[row * 132 + c4 * 4];
        __builtin_nontemporal_store(
            v, (f32x4*)&outF[(size_t)(m0 + s * 128 + row) * (size_t)N + n0 + c4 * 4]);
      }
    }
  } else {
    // ---- mgemm: M-partials = sdT sdT^T, two 256-thread groups per block ----
    const int tt = bid;                   // 0..127
    const int g = tid >> 8;               // group 0/1
    const int lt = tid & 255;
    const int q = tt * 2 + g;             // 0..255 tile index
    const int i0 = (q & 7) * 128;
    const int j0 = ((q >> 3) & 7) * 128;
    const int kt0 = (q >> 6) * 64;
    constexpr int Kt = 8192, Dm = 1024;

    ushortT* pool = smem + g * 16384;     // 32768 B per group
    ushortT(*sA)[128 * 32] = (ushortT(*)[128 * 32])pool;
    ushortT(*sB)[128 * 32] = (ushortT(*)[128 * 32])(pool + 2 * 128 * 32);

    const int w = lt >> 6, l = lt & 63;
    const int wr = w >> 1, wc = w & 1;
    f32x4 acc[4][4] = {};

    const int sgm = ((l & 3) ^ ((l >> 3) & 3)) << 3;  // swizzled src granule

    auto stage = [&](int buf, int kt) {
      const size_t col = (size_t)((kt << 5) + sgm);
      const int rb = w * 16 + (l >> 2);
#pragma unroll
      for (int c = 0; c < 2; ++c) {
        gl_lds16(T + (size_t)(i0 + c * 64 + rb) * (size_t)Kt + col,
                 &sA[buf][c * 2048 + w * 512]);
        gl_lds16(T + (size_t)(j0 + c * 64 + rb) * (size_t)Kt + col,
                 &sB[buf][c * 2048 + w * 512]);
      }
    };

    const int fr = l & 15;
    const int colsw = (((l >> 4) ^ ((fr >> 1) & 3)) << 3);

    stage(0, kt0);
    __syncthreads();

    for (int t = 0; t < 64; ++t) {
      const int buf = t & 1;
      if (t + 1 < 64) stage(buf ^ 1, kt0 + t + 1);
      short8 a[4], b[4];
#pragma unroll
      for (int f = 0; f < 4; ++f) {
        a[f] = *(const short8*)&sA[buf][(wr * 64 + f * 16 + fr) * 32 + colsw];
        b[f] = *(const short8*)&sB[buf][(wc * 64 + f * 16 + fr) * 32 + colsw];
      }
#pragma unroll
      for (int fi = 0; fi < 4; ++fi)
#pragma unroll
        for (int fj = 0; fj < 4; ++fj)
          acc[fi][fj] = __builtin_amdgcn_mfma_f32_16x16x32_bf16(
              a[fi], b[fj], acc[fi][fj], 0, 0, 0);
      __syncthreads();
    }

    const int r4 = (l >> 4) * 4, cc = l & 15;
    float* out = pbuf + ((size_t)(q >> 6) << 20);
#pragma unroll
    for (int fi = 0; fi < 4; ++fi)
#pragma unroll
      for (int r = 0; r < 4; ++r) {
        const int gi = i0 + wr * 64 + fi * 16 + r4 + r;
#pragma unroll
        for (int fj = 0; fj < 4; ++fj) {
          const int gj = j0 + wc * 64 + fj * 16 + cc;
          out[(size_t)gi * (size_t)Dm + gj] = acc[fi][fj][r];
        }
      }
  }
}

// ===== fused_sd + cvt_x: blocks [0,128) W@Q | [128,640) sd | [640,2688) =====
__global__ __launch_bounds__(256) void fused_sd(
    const ushortT* __restrict__ wbf, const ushortT* __restrict__ qT,
    ushortT* __restrict__ fusedbf,
    const ushortT* __restrict__ selbf, const ushortT* __restrict__ pbf,
    const float* __restrict__ addend,
    float* __restrict__ S2, float* __restrict__ S4,
    ushortT* __restrict__ sdT,
    const float* __restrict__ x, ushortT* __restrict__ xbf)
{
  __shared__ ushortT smem[17408];  // 34816 B: sA|sB (32768) aliased by tbuf
  const int tid = threadIdx.x;
  const int bid = blockIdx.x;

  if (bid >= 640) {  // ---- cvt_x: 2048 blocks, 201 MB stream ----
    const f32x4* in4 = (const f32x4*)x;
    for (size_t i = (size_t)(bid - 640) * 256 + tid; i < 8388608ULL;
         i += 2048ULL * 256) {
      f32x4 v = __builtin_nontemporal_load(&in4[i]);
      us4 o = { f2bf(v[0]), f2bf(v[1]), f2bf(v[2]), f2bf(v[3]) };
      *(us4*)(xbf + i * 4) = o;
    }
    return;
  }

  ushortT(*sA)[128 * 32] = (ushortT(*)[128 * 32])smem;
  ushortT(*sB)[128 * 32] = (ushortT(*)[128 * 32])(smem + 2 * 128 * 32);
  ushortT* tbuf = smem;  // epilogue-only alias

  const int w = tid >> 6, l = tid & 63;
  const int wr = w >> 1, wc = w & 1;
  constexpr int K = 1024, NK = 32, N = 1024;

  const bool isF = bid < 128;
  const int q = isF ? bid : bid - 128;
  const int m0 = isF ? (q & 15) * 128 : (q & 63) * 128;
  const int n0 = isF ? (q >> 4) * 128 : (q >> 6) * 128;
  const ushortT* A = isF ? wbf : selbf;
  const ushortT* B = isF ? qT : pbf;

  f32x4 acc[4][4] = {};

  const int sgm = ((l & 3) ^ ((l >> 3) & 3)) << 3;  // swizzled src granule

  auto stage = [&](int buf, int kt) {
    const size_t colA = (size_t)((kt << 5) + sgm);
    const int rb = w * 16 + (l >> 2);
#pragma unroll
    for (int c = 0; c < 2; ++c) {
      gl_lds16(A + (size_t)(m0 + c * 64 + rb) * (size_t)K + colA,
               &sA[buf][c * 2048 + w * 512]);
      gl_lds16(B + (size_t)(n0 + c * 64 + rb) * (size_t)K + colA,
               &sB[buf][c * 2048 + w * 512]);
    }
  };

  const int fr = l & 15;
  const int colsw = (((l >> 4) ^ ((fr >> 1) & 3)) << 3);

  stage(0, 0);
  __syncthreads();

  for (int kt = 0; kt < NK; ++kt) {
    const int buf = kt & 1;
    if (kt + 1 < NK) stage(buf ^ 1, kt + 1);
    short8 a[4], b[4];
#pragma unroll
    for (int f = 0; f < 4; ++f) {
      a[f] = *(const short8*)&sA[buf][(wr * 64 + f * 16 + fr) * 32 + colsw];
      b[f] = *(const short8*)&sB[buf][(wc * 64 + f * 16 + fr) * 32 + colsw];
    }
#pragma unroll
    for (int fi = 0; fi < 4; ++fi)
#pragma unroll
      for (int fj = 0; fj < 4; ++fj)
        acc[fi][fj] = __builtin_amdgcn_mfma_f32_16x16x32_bf16(
            a[fi], b[fj], acc[fi][fj], 0, 0, 0);
    __syncthreads();
  }

  const int r4 = (l >> 4) * 4, cc = l & 15;

  if (isF) {
#pragma unroll
    for (int fi = 0; fi < 4; ++fi)
#pragma unroll
      for (int r = 0; r < 4; ++r) {
        const size_t gm = (size_t)(m0 + wr * 64 + fi * 16 + r4 + r);
#pragma unroll
        for (int fj = 0; fj < 4; ++fj) {
          const int gn = n0 + wc * 64 + fj * 16 + cc;
          fusedbf[gm * (size_t)N + gn] = f2bf(acc[fi][fj][r]);
        }
      }
  } else {
#pragma unroll
    for (int fi = 0; fi < 4; ++fi)
#pragma unroll
      for (int r = 0; r < 4; ++r) {
        const int row = wr * 64 + fi * 16 + r4 + r;
        const size_t gm = (size_t)(m0 + row);
        float rs2 = 0.f, rs4 = 0.f;
#pragma unroll
        for (int fj = 0; fj < 4; ++fj) {
          const int col = wc * 64 + fj * 16 + cc;
          float sd = acc[fi][fj][r] + addend[gm * (size_t)N + n0 + col];
          tbuf[col * 136 + row] = f2bf(sd);
          float s2 = sd * sd;
          rs2 += s2;
          rs4 += s2 * s2;
        }
#pragma unroll
        for (int mk = 1; mk < 16; mk <<= 1) {
          rs2 += __shfl_xor(rs2, mk, 16);
          rs4 += __shfl_xor(rs4, mk, 16);
        }
        if (cc == 0) { atomicAdd(&S2[gm], rs2); atomicAdd(&S4[gm], rs4); }
      }
    __syncthreads();
#pragma unroll
    for (int i = 0; i < 8; ++i) {
      const int er = i * 16 + (tid >> 4);
      const int nc = (tid & 15) * 8;
      short8 v = *(const short8*)&tbuf[er * 136 + nc];
      *(short8*)&sdT[(size_t)(n0 + er) * 8192 + m0 + nc] = v;
    }
  }
}

// ---- merged finalize: grad reduce (blocks 0..1023) + losses (block 1024) ----
__global__ __launch_bounds__(256) void finalize(
    const float* __restrict__ pbuf, float* __restrict__ grad, float invN,
    const float* __restrict__ S2, const float* __restrict__ S4,
    float* __restrict__ losses)
{
  __shared__ double red0[256];
  __shared__ double red1[256];
  const int t = threadIdx.x;
  if (blockIdx.x < 1024) {
    const int i = blockIdx.x * 256 + t;
    const size_t base = (size_t)i * 4;
    f32x4 s = *(const f32x4*)(pbuf + base) + *(const f32x4*)(pbuf + base + (1u << 20)) +
              *(const f32x4*)(pbuf + base + (2u << 20)) + *(const f32x4*)(pbuf + base + (3u << 20));
    const int row = (int)(base >> 10), c0 = (int)(base & 1023);
    f32x4 o;
#pragma unroll
    for (int j = 0; j < 4; ++j)
      o[j] = 0.5f * (s[j] * invN) - ((row == c0 + j) ? 0.5f : 0.0f);
    *(f32x4*)(grad + base) = o;
  } else {
    double ca = 0.0, wa = 0.0;
    for (int i = t; i < 8192; i += 256) {
      double s2 = (double)S2[i], s4 = (double)S4[i];
      ca += s2 * s2 - s4;
      wa += s4 - 2.0 * s2 + 1024.0;
    }
    red0[t] = ca; red1[t] = wa;
    __syncthreads();
    for (int s = 128; s > 0; s >>= 1) {
      if (t < s) { red0[t] += red0[t + s]; red1[t] += red1[t + s]; }
      __syncthreads();
    }
    if (t == 0) {
      const double inv = 1.0 / (8192.0 * 1024.0 * 1024.0);
      losses[0] = (float)(red0[0] * inv);
      losses[1] = (float)(red1[0] * inv);
    }
  }
}

// ==== prep (no cvt_x): cvt_w | make P | transpose Q | zero | gather =========
__global__ __launch_bounds__(256) void prep_all(
    const float* __restrict__ x, const float* __restrict__ weight,
    const float* __restrict__ decorr, const int* __restrict__ idx,
    ushortT* __restrict__ wbf, ushortT* __restrict__ qT,
    ushortT* __restrict__ pbf, float* __restrict__ S2S4,
    float* __restrict__ self32, ushortT* __restrict__ selbf)
{
  __shared__ float t[64][65];
  const int bid = blockIdx.x;
  const int tix = threadIdx.x;
  if (bid < 512) {
    const f32x4* in4 = (const f32x4*)weight;
    for (size_t i = (size_t)bid * 256 + tix; i < 524288ULL; i += 512ULL * 256) {
      f32x4 v = in4[i];
      us4 o = { f2bf(v[0]), f2bf(v[1]), f2bf(v[2]), f2bf(v[3]) };
      *(us4*)(wbf + i * 4) = o;
    }
  } else if (bid < 1024) {
    const size_t base = ((size_t)(bid - 512) * 256 + tix) * 8;
    const int e = (int)(base >> 10);
    const int d0 = (int)(base & 1023);
    short8 v;
#pragma unroll
    for (int j = 0; j < 8; ++j) {
      float f = decorr[base + j] - ((e == d0 + j) ? 1.0f : 0.0f);
      v[j] = (short)f2bf(f);
    }
    *(short8*)(pbf + base) = v;
  } else if (bid < 1280) {
    const int tq = bid - 1024;
    const int bi = tq & 15, bj = tq >> 4;
    const int tr = tix >> 4, tc = tix & 15;
#pragma unroll
    for (int i = 0; i < 4; ++i) {
      const int row = i * 16 + tr;
      f32x4 v = *(const f32x4*)&decorr[(size_t)(bi * 64 + row) * 1024 + bj * 64 + tc * 4];
#pragma unroll
      for (int j = 0; j < 4; ++j) t[row][tc * 4 + j] = v[j];
    }
    __syncthreads();
#pragma unroll
    for (int i = 0; i < 4; ++i) {
      const int dr = i * 16 + tr;
      us4 o = { f2bf(t[tc * 4 + 0][dr]), f2bf(t[tc * 4 + 1][dr]),
                f2bf(t[tc * 4 + 2][dr]), f2bf(t[tc * 4 + 3][dr]) };
      *(us4*)&qT[(size_t)(bj * 64 + dr) * 1024 + bi * 64 + tc * 4] = o;
    }
  } else if (bid < 1344) {
    S2S4[(bid - 1280) * 256 + tix] = 0.f;
  } else {
    const int g = bid - 1344;                // 0..8191
    const int b = g >> 10;
    const int row = idx[g] & 4095;
    const f32x4* src = (const f32x4*)(x + ((size_t)b * 4096 + (size_t)row) * 1024);
    f32x4 v = src[tix];
    *(f32x4*)(self32 + (size_t)g * 1024 + tix * 4) = v;
    us4 o = { f2bf(v[0]), f2bf(v[1]), f2bf(v[2]), f2bf(v[3]) };
    *(us4*)(selbf + (size_t)g * 1024 + tix * 4) = o;
  }
}

// ---------------- launch -----------------------------------------------------
extern "C" void kernel_launch(void* const* d_in, const int* in_sizes, int n_in,
                              void* d_out, int out_size, void* d_ws, size_t ws_size,
                              hipStream_t stream) {
  (void)in_sizes; (void)n_in; (void)out_size;
  const float* x = (const float*)d_in[0];
  const float* weight = (const float*)d_in[1];
  const float* bias = (const float*)d_in[2];
  const float* decorr = (const float*)d_in[3];
  const int* sidx = (const int*)d_in[4];

  if (ws_size < 146866176ULL) return;

  char* ws = (char*)d_ws;
  ushortT* xbf     = (ushortT*)(ws);
  ushortT* fusedbf = (ushortT*)(ws + 67108864);
  ushortT* wbf     = (ushortT*)(ws + 71303168);
  ushortT* qT      = (ushortT*)(ws + 75497472);
  ushortT* pbf     = (ushortT*)(ws + 77594624);
  float*   self32  = (float*)  (ws + 79691776);
  ushortT* selbf   = (ushortT*)(ws + 113246208);
  ushortT* sdT     = (ushortT*)(ws + 130023424);
  float*   S2      = (float*)  (ws + 146800640);
  float*   S4      = (float*)  (ws + 146833408);

  float* y = (float*)d_out;
  float* grad = y + 67108864ULL;
  float* losses = grad + 1048576ULL;

  // prep (no cvt_x): cvt_w | P | Q^T | zero | gather
  prep_all<<<dim3(9536), dim3(256), 0, stream>>>(
      x, weight, decorr, sidx, wbf, qT, pbf, S2, self32, selbf);

  // W@Q || sd-GEMM (+S2/S4, sdT) || cvt_x stream
  fused_sd<<<dim3(2688), dim3(256), 0, stream>>>(
      wbf, qT, fusedbf, selbf, pbf, self32, S2, S4, sdT, x, xbf);

  // M-partials (blocks 0..127, run early) || y = x@fused^T + bias (128..2175)
  gemm_mg<<<dim3(2176), dim3(512), 0, stream>>>(
      xbf, fusedbf, y, bias, sdT, self32);

  // grad reduce + losses
  finalize<<<dim3(1025), dim3(256), 0, stream>>>(
      self32, grad, 1.0f / 8192.0f, S2, S4, losses);
}

// Round 18
// 266.448 us; speedup vs baseline: 1.0884x; 1.0176x over previous
//
#include <hip/hip_runtime.h>
#include <hip/hip_bf16.h>
#include <cstdint>

typedef unsigned short ushortT;
typedef __attribute__((ext_vector_type(8))) short short8;
typedef __attribute__((ext_vector_type(4))) float f32x4;
typedef __attribute__((ext_vector_type(4))) unsigned short us4;

__device__ __forceinline__ ushortT f2bf(float f) {
  union { float f; unsigned u; } v; v.f = f;
  unsigned r = (v.u + 0x7FFFu + ((v.u >> 16) & 1u)) >> 16;
  return (ushortT)r;
}

__device__ __forceinline__ void gl_lds16(const void* g, void* l) {
  __builtin_amdgcn_global_load_lds(
      (__attribute__((address_space(1))) void*)g,
      (__attribute__((address_space(3))) void*)l, 16, 0, 0);
}

// ==== gemm_mg: blocks [0,128) = mgemm128sk (first -> packs with gemm256's
// first occupancy wave); blocks [128,2176) = r8/r13 gemm256 (proven path).
__global__ __launch_bounds__(512, 2) void gemm_mg(
    const ushortT* __restrict__ A, const ushortT* __restrict__ B,
    float* __restrict__ outF, const float* __restrict__ bias,
    const ushortT* __restrict__ T, float* __restrict__ pbuf)
{
  __shared__ ushortT smem[36864];  // 73728 B pool
  const int tid = threadIdx.x;
  const int bid = blockIdx.x;
  constexpr int N = 2048, K = 1024;

  if (bid >= 128) {
    // ---------------- gemm256: y = x @ fused^T + bias ----------------
    ushortT(*sA)[256 * 32] = (ushortT(*)[256 * 32])smem;
    ushortT(*sB)[128 * 32] = (ushortT(*)[128 * 32])(smem + 3 * 256 * 32);

    const int wv = tid >> 6, l = tid & 63;
    const int wm = wv >> 1, wn = wv & 1;

    const int gb = bid - 128;            // 0..2047, 128%8==0 keeps swizzle
    const int xcd = gb & 7, i = gb >> 3;
    const int n0 = (i & 15) * 128;
    const int m0 = (xcd * 16 + (i >> 4)) * 256;
    const int NK = K >> 5;

    f32x4 acc[4][4] = {};

    const ushortT* Ab = A + (size_t)m0 * (size_t)K;
    const ushortT* Bb = B + (size_t)n0 * (size_t)K;

    const int sr = tid >> 2;
    const int sg = tid & 3;
    const int gsw = sg ^ ((sr >> 1) & 3);

    auto stage = [&](int kt) {
      const int b = kt % 3;
      const size_t kof = (size_t)((kt << 5) + (gsw << 3));
      gl_lds16(Ab + (size_t)sr * (size_t)K + kof,         &sA[b][(wv * 16) * 32]);
      gl_lds16(Ab + (size_t)(128 + sr) * (size_t)K + kof, &sA[b][(128 + wv * 16) * 32]);
      gl_lds16(Bb + (size_t)sr * (size_t)K + kof,         &sB[b][(wv * 16) * 32]);
    };

    const int fr = l & 15;
    const int colsw = (((l >> 4) ^ ((fr >> 1) & 3)) << 3);

    stage(0);
    stage(1);

    for (int kt = 0; kt < NK; ++kt) {
      if (kt + 1 < NK) asm volatile("s_waitcnt vmcnt(3)" ::: "memory");
      else             asm volatile("s_waitcnt vmcnt(0)" ::: "memory");
      __builtin_amdgcn_s_barrier();
      if (kt + 2 < NK) stage(kt + 2);

      const int bc = kt % 3;
      short8 av[4], bv8[4];
#pragma unroll
      for (int fi = 0; fi < 4; ++fi)
        av[fi] = *(const short8*)&sA[bc][(wm * 64 + fi * 16 + fr) * 32 + colsw];
#pragma unroll
      for (int fj = 0; fj < 4; ++fj)
        bv8[fj] = *(const short8*)&sB[bc][(wn * 64 + fj * 16 + fr) * 32 + colsw];

      __builtin_amdgcn_s_setprio(1);
#pragma unroll
      for (int fi = 0; fi < 4; ++fi)
#pragma unroll
        for (int fj = 0; fj < 4; ++fj)
          acc[fi][fj] = __builtin_amdgcn_mfma_f32_16x16x32_bf16(
              av[fi], bv8[fj], acc[fi][fj], 0, 0, 0);
      __builtin_amdgcn_s_setprio(0);
    }

    const int cc = l & 15, r4 = (l >> 4) * 4;
    float bvv[4];
#pragma unroll
    for (int fj = 0; fj < 4; ++fj) bvv[fj] = bias[n0 + wn * 64 + fj * 16 + cc];

    float* lbuf = (float*)smem;
#pragma unroll
    for (int s = 0; s < 2; ++s) {
      __syncthreads();
      if ((wm >> 1) == s) {
#pragma unroll
        for (int fi = 0; fi < 4; ++fi)
#pragma unroll
          for (int r = 0; r < 4; ++r) {
            const int row = (wm & 1) * 64 + fi * 16 + r4 + r;
#pragma unroll
            for (int fj = 0; fj < 4; ++fj)
              lbuf[row * 132 + wn * 64 + fj * 16 + cc] = acc[fi][fj][r] + bvv[fj];
          }
      }
      __syncthreads();
#pragma unroll
      for (int k = 0; k < 8; ++k) {
        const int f = k * 512 + tid;
        const int row = f >> 5, c4 = f & 31;
        f32x4 v = *(const f32x4*)&lbuf[row * 132 + c4 * 4];
        __builtin_nontemporal_store(
            v, (f32x4*)&outF[(size_t)(m0 + s * 128 + row) * (size_t)N + n0 + c4 * 4]);
      }
    }
  } else {
    // ---- mgemm: M-partials = sdT sdT^T, two 256-thread groups per block ----
    const int tt = bid;                   // 0..127
    const int g = tid >> 8;               // group 0/1
    const int lt = tid & 255;
    const int q = tt * 2 + g;             // 0..255 tile index
    const int i0 = (q & 7) * 128;
    const int j0 = ((q >> 3) & 7) * 128;
    const int kt0 = (q >> 6) * 64;
    constexpr int Kt = 8192, Dm = 1024;

    ushortT* pool = smem + g * 16384;     // 32768 B per group
    ushortT(*sA)[128 * 32] = (ushortT(*)[128 * 32])pool;
    ushortT(*sB)[128 * 32] = (ushortT(*)[128 * 32])(pool + 2 * 128 * 32);

    const int w = lt >> 6, l = lt & 63;
    const int wr = w >> 1, wc = w & 1;
    f32x4 acc[4][4] = {};

    const int sgm = ((l & 3) ^ ((l >> 3) & 3)) << 3;  // swizzled src granule

    auto stage = [&](int buf, int kt) {
      const size_t col = (size_t)((kt << 5) + sgm);
      const int rb = w * 16 + (l >> 2);
#pragma unroll
      for (int c = 0; c < 2; ++c) {
        gl_lds16(T + (size_t)(i0 + c * 64 + rb) * (size_t)Kt + col,
                 &sA[buf][c * 2048 + w * 512]);
        gl_lds16(T + (size_t)(j0 + c * 64 + rb) * (size_t)Kt + col,
                 &sB[buf][c * 2048 + w * 512]);
      }
    };

    const int fr = l & 15;
    const int colsw = (((l >> 4) ^ ((fr >> 1) & 3)) << 3);

    stage(0, kt0);
    __syncthreads();

    for (int t = 0; t < 64; ++t) {
      const int buf = t & 1;
      if (t + 1 < 64) stage(buf ^ 1, kt0 + t + 1);
      short8 a[4], b[4];
#pragma unroll
      for (int f = 0; f < 4; ++f) {
        a[f] = *(const short8*)&sA[buf][(wr * 64 + f * 16 + fr) * 32 + colsw];
        b[f] = *(const short8*)&sB[buf][(wc * 64 + f * 16 + fr) * 32 + colsw];
      }
#pragma unroll
      for (int fi = 0; fi < 4; ++fi)
#pragma unroll
        for (int fj = 0; fj < 4; ++fj)
          acc[fi][fj] = __builtin_amdgcn_mfma_f32_16x16x32_bf16(
              a[fi], b[fj], acc[fi][fj], 0, 0, 0);
      __syncthreads();
    }

    const int r4 = (l >> 4) * 4, cc = l & 15;
    float* out = pbuf + ((size_t)(q >> 6) << 20);
#pragma unroll
    for (int fi = 0; fi < 4; ++fi)
#pragma unroll
      for (int r = 0; r < 4; ++r) {
        const int gi = i0 + wr * 64 + fi * 16 + r4 + r;
#pragma unroll
        for (int fj = 0; fj < 4; ++fj) {
          const int gj = j0 + wc * 64 + fj * 16 + cc;
          out[(size_t)gi * (size_t)Dm + gj] = acc[fi][fj][r];
        }
      }
  }
}

// ===== fused_sd + cvt_x: blocks [0,128) W@Q | [128,640) sd | [640,2688) =====
// sd epilogue reads addend rows directly from x via idx (self32 copy removed).
__global__ __launch_bounds__(256) void fused_sd(
    const ushortT* __restrict__ wbf, const ushortT* __restrict__ qT,
    ushortT* __restrict__ fusedbf,
    const ushortT* __restrict__ selbf, const ushortT* __restrict__ pbf,
    const int* __restrict__ idx,
    float* __restrict__ S2, float* __restrict__ S4,
    ushortT* __restrict__ sdT,
    const float* __restrict__ x, ushortT* __restrict__ xbf)
{
  __shared__ ushortT smem[17408];  // 34816 B: sA|sB (32768) aliased by tbuf
  const int tid = threadIdx.x;
  const int bid = blockIdx.x;

  if (bid >= 640) {  // ---- cvt_x: 2048 blocks, 201 MB stream ----
    const f32x4* in4 = (const f32x4*)x;
    for (size_t i = (size_t)(bid - 640) * 256 + tid; i < 8388608ULL;
         i += 2048ULL * 256) {
      f32x4 v = __builtin_nontemporal_load(&in4[i]);
      us4 o = { f2bf(v[0]), f2bf(v[1]), f2bf(v[2]), f2bf(v[3]) };
      *(us4*)(xbf + i * 4) = o;
    }
    return;
  }

  ushortT(*sA)[128 * 32] = (ushortT(*)[128 * 32])smem;
  ushortT(*sB)[128 * 32] = (ushortT(*)[128 * 32])(smem + 2 * 128 * 32);
  ushortT* tbuf = smem;  // epilogue-only alias

  const int w = tid >> 6, l = tid & 63;
  const int wr = w >> 1, wc = w & 1;
  constexpr int K = 1024, NK = 32, N = 1024;

  const bool isF = bid < 128;
  const int q = isF ? bid : bid - 128;
  const int m0 = isF ? (q & 15) * 128 : (q & 63) * 128;
  const int n0 = isF ? (q >> 4) * 128 : (q >> 6) * 128;
  const ushortT* A = isF ? wbf : selbf;
  const ushortT* B = isF ? qT : pbf;

  f32x4 acc[4][4] = {};

  const int sgm = ((l & 3) ^ ((l >> 3) & 3)) << 3;  // swizzled src granule

  auto stage = [&](int buf, int kt) {
    const size_t colA = (size_t)((kt << 5) + sgm);
    const int rb = w * 16 + (l >> 2);
#pragma unroll
    for (int c = 0; c < 2; ++c) {
      gl_lds16(A + (size_t)(m0 + c * 64 + rb) * (size_t)K + colA,
               &sA[buf][c * 2048 + w * 512]);
      gl_lds16(B + (size_t)(n0 + c * 64 + rb) * (size_t)K + colA,
               &sB[buf][c * 2048 + w * 512]);
    }
  };

  const int fr = l & 15;
  const int colsw = (((l >> 4) ^ ((fr >> 1) & 3)) << 3);

  stage(0, 0);
  __syncthreads();

  for (int kt = 0; kt < NK; ++kt) {
    const int buf = kt & 1;
    if (kt + 1 < NK) stage(buf ^ 1, kt + 1);
    short8 a[4], b[4];
#pragma unroll
    for (int f = 0; f < 4; ++f) {
      a[f] = *(const short8*)&sA[buf][(wr * 64 + f * 16 + fr) * 32 + colsw];
      b[f] = *(const short8*)&sB[buf][(wc * 64 + f * 16 + fr) * 32 + colsw];
    }
#pragma unroll
    for (int fi = 0; fi < 4; ++fi)
#pragma unroll
      for (int fj = 0; fj < 4; ++fj)
        acc[fi][fj] = __builtin_amdgcn_mfma_f32_16x16x32_bf16(
            a[fi], b[fj], acc[fi][fj], 0, 0, 0);
    __syncthreads();
  }

  const int r4 = (l >> 4) * 4, cc = l & 15;

  if (isF) {
#pragma unroll
    for (int fi = 0; fi < 4; ++fi)
#pragma unroll
      for (int r = 0; r < 4; ++r) {
        const size_t gm = (size_t)(m0 + wr * 64 + fi * 16 + r4 + r);
#pragma unroll
        for (int fj = 0; fj < 4; ++fj) {
          const int gn = n0 + wc * 64 + fj * 16 + cc;
          fusedbf[gm * (size_t)N + gn] = f2bf(acc[fi][fj][r]);
        }
      }
  } else {
#pragma unroll
    for (int fi = 0; fi < 4; ++fi)
#pragma unroll
      for (int r = 0; r < 4; ++r) {
        const int row = wr * 64 + fi * 16 + r4 + r;
        const int grow = m0 + row;                  // sd row 0..8191
        const int xb = grow >> 10;
        const int xr = idx[grow] & 4095;
        const float* arow = x + ((size_t)xb * 4096 + (size_t)xr) * 1024 + n0;
        float rs2 = 0.f, rs4 = 0.f;
#pragma unroll
        for (int fj = 0; fj < 4; ++fj) {
          const int col = wc * 64 + fj * 16 + cc;
          float sd = acc[fi][fj][r] + arow[col];
          tbuf[col * 136 + row] = f2bf(sd);
          float s2 = sd * sd;
          rs2 += s2;
          rs4 += s2 * s2;
        }
#pragma unroll
        for (int mk = 1; mk < 16; mk <<= 1) {
          rs2 += __shfl_xor(rs2, mk, 16);
          rs4 += __shfl_xor(rs4, mk, 16);
        }
        if (cc == 0) { atomicAdd(&S2[grow], rs2); atomicAdd(&S4[grow], rs4); }
      }
    __syncthreads();
#pragma unroll
    for (int i = 0; i < 8; ++i) {
      const int er = i * 16 + (tid >> 4);
      const int nc = (tid & 15) * 8;
      short8 v = *(const short8*)&tbuf[er * 136 + nc];
      *(short8*)&sdT[(size_t)(n0 + er) * 8192 + m0 + nc] = v;
    }
  }
}

// ---- merged finalize: grad reduce (blocks 0..1023) + losses (block 1024) ----
__global__ __launch_bounds__(256) void finalize(
    const float* __restrict__ pbuf, float* __restrict__ grad, float invN,
    const float* __restrict__ S2, const float* __restrict__ S4,
    float* __restrict__ losses)
{
  __shared__ double red0[256];
  __shared__ double red1[256];
  const int t = threadIdx.x;
  if (blockIdx.x < 1024) {
    const int i = blockIdx.x * 256 + t;
    const size_t base = (size_t)i * 4;
    f32x4 s = *(const f32x4*)(pbuf + base) + *(const f32x4*)(pbuf + base + (1u << 20)) +
              *(const f32x4*)(pbuf + base + (2u << 20)) + *(const f32x4*)(pbuf + base + (3u << 20));
    const int row = (int)(base >> 10), c0 = (int)(base & 1023);
    f32x4 o;
#pragma unroll
    for (int j = 0; j < 4; ++j)
      o[j] = 0.5f * (s[j] * invN) - ((row == c0 + j) ? 0.5f : 0.0f);
    *(f32x4*)(grad + base) = o;
  } else {
    double ca = 0.0, wa = 0.0;
    for (int i = t; i < 8192; i += 256) {
      double s2 = (double)S2[i], s4 = (double)S4[i];
      ca += s2 * s2 - s4;
      wa += s4 - 2.0 * s2 + 1024.0;
    }
    red0[t] = ca; red1[t] = wa;
    __syncthreads();
    for (int s = 128; s > 0; s >>= 1) {
      if (t < s) { red0[t] += red0[t + s]; red1[t] += red1[t + s]; }
      __syncthreads();
    }
    if (t == 0) {
      const double inv = 1.0 / (8192.0 * 1024.0 * 1024.0);
      losses[0] = (float)(red0[0] * inv);
      losses[1] = (float)(red1[0] * inv);
    }
  }
}

// ==== prep: cvt_w | make P | transpose Q | zero | gather (selbf only) =======
__global__ __launch_bounds__(256) void prep_all(
    const float* __restrict__ x, const float* __restrict__ weight,
    const float* __restrict__ decorr, const int* __restrict__ idx,
    ushortT* __restrict__ wbf, ushortT* __restrict__ qT,
    ushortT* __restrict__ pbf, float* __restrict__ S2S4,
    ushortT* __restrict__ selbf)
{
  __shared__ float t[64][65];
  const int bid = blockIdx.x;
  const int tix = threadIdx.x;
  if (bid < 512) {
    const f32x4* in4 = (const f32x4*)weight;
    for (size_t i = (size_t)bid * 256 + tix; i < 524288ULL; i += 512ULL * 256) {
      f32x4 v = in4[i];
      us4 o = { f2bf(v[0]), f2bf(v[1]), f2bf(v[2]), f2bf(v[3]) };
      *(us4*)(wbf + i * 4) = o;
    }
  } else if (bid < 1024) {
    const size_t base = ((size_t)(bid - 512) * 256 + tix) * 8;
    const int e = (int)(base >> 10);
    const int d0 = (int)(base & 1023);
    short8 v;
#pragma unroll
    for (int j = 0; j < 8; ++j) {
      float f = decorr[base + j] - ((e == d0 + j) ? 1.0f : 0.0f);
      v[j] = (short)f2bf(f);
    }
    *(short8*)(pbf + base) = v;
  } else if (bid < 1280) {
    const int tq = bid - 1024;
    const int bi = tq & 15, bj = tq >> 4;
    const int tr = tix >> 4, tc = tix & 15;
#pragma unroll
    for (int i = 0; i < 4; ++i) {
      const int row = i * 16 + tr;
      f32x4 v = *(const f32x4*)&decorr[(size_t)(bi * 64 + row) * 1024 + bj * 64 + tc * 4];
#pragma unroll
      for (int j = 0; j < 4; ++j) t[row][tc * 4 + j] = v[j];
    }
    __syncthreads();
#pragma unroll
    for (int i = 0; i < 4; ++i) {
      const int dr = i * 16 + tr;
      us4 o = { f2bf(t[tc * 4 + 0][dr]), f2bf(t[tc * 4 + 1][dr]),
                f2bf(t[tc * 4 + 2][dr]), f2bf(t[tc * 4 + 3][dr]) };
      *(us4*)&qT[(size_t)(bj * 64 + dr) * 1024 + bi * 64 + tc * 4] = o;
    }
  } else if (bid < 1344) {
    S2S4[(bid - 1280) * 256 + tix] = 0.f;
  } else {
    const int g = bid - 1344;                // 0..8191
    const int b = g >> 10;
    const int row = idx[g] & 4095;
    const f32x4* src = (const f32x4*)(x + ((size_t)b * 4096 + (size_t)row) * 1024);
    f32x4 v = src[tix];
    us4 o = { f2bf(v[0]), f2bf(v[1]), f2bf(v[2]), f2bf(v[3]) };
    *(us4*)(selbf + (size_t)g * 1024 + tix * 4) = o;
  }
}

// ---------------- launch -----------------------------------------------------
extern "C" void kernel_launch(void* const* d_in, const int* in_sizes, int n_in,
                              void* d_out, int out_size, void* d_ws, size_t ws_size,
                              hipStream_t stream) {
  (void)in_sizes; (void)n_in; (void)out_size;
  const float* x = (const float*)d_in[0];
  const float* weight = (const float*)d_in[1];
  const float* bias = (const float*)d_in[2];
  const float* decorr = (const float*)d_in[3];
  const int* sidx = (const int*)d_in[4];

  if (ws_size < 146866176ULL) return;

  char* ws = (char*)d_ws;
  ushortT* xbf     = (ushortT*)(ws);
  ushortT* fusedbf = (ushortT*)(ws + 67108864);
  ushortT* wbf     = (ushortT*)(ws + 71303168);
  ushortT* qT      = (ushortT*)(ws + 75497472);
  ushortT* pbf     = (ushortT*)(ws + 77594624);
  float*   pkbuf   = (float*)  (ws + 79691776);   // split-K partials (16 MB)
  ushortT* selbf   = (ushortT*)(ws + 113246208);
  ushortT* sdT     = (ushortT*)(ws + 130023424);
  float*   S2      = (float*)  (ws + 146800640);
  float*   S4      = (float*)  (ws + 146833408);

  float* y = (float*)d_out;
  float* grad = y + 67108864ULL;
  float* losses = grad + 1048576ULL;

  // prep: cvt_w | P | Q^T | zero | gather (selbf only)
  prep_all<<<dim3(9536), dim3(256), 0, stream>>>(
      x, weight, decorr, sidx, wbf, qT, pbf, S2, selbf);

  // W@Q || sd-GEMM (+S2/S4, sdT; addend from x via idx) || cvt_x stream
  fused_sd<<<dim3(2688), dim3(256), 0, stream>>>(
      wbf, qT, fusedbf, selbf, pbf, sidx, S2, S4, sdT, x, xbf);

  // M-partials (blocks 0..127, run early) || y = x@fused^T + bias (128..2175)
  gemm_mg<<<dim3(2176), dim3(512), 0, stream>>>(
      xbf, fusedbf, y, bias, sdT, pkbuf);

  // grad reduce + losses
  finalize<<<dim3(1025), dim3(256), 0, stream>>>(
      pkbuf, grad, 1.0f / 8192.0f, S2, S4, losses);
}